// Round 8
// baseline (5771.240 us; speedup 1.0000x reference)
//
#include <hip/hip_runtime.h>

// ReservoirLayer: S0 = pad(x,[2048,4096]); 16x: S = leaky_relu(S @ W, 0.1)
// fp32-emulation via fp16 hi/lo split (fp16x3): acc = Sh@Wh + Sl@Wh + Sh@Wl.
// R8: BARRIER-FREE K-loop.
//  - B (=256*W^T hi/lo) stored in fragment-native swizzled layout
//    Bswz[kc][jg][lane][e]; a B-frag is ONE global_load_dwordx4 reading 1 KB
//    CONTIGUOUS (16 fully-consumed lines). No LDS for B.
//  - Wave tile 32x128: each wave's 32 A-rows are wave-private; staged via
//    global_load_lds into a private LDS region, synced by the wave's own
//    s_waitcnt vmcnt(0) (drains a stage issued one full iter earlier -> free).
//  - No __syncthreads anywhere in the K-loop => no forced drains, no
//    phase-lock; LDS traffic cut from 192 KB to 64 KB per CU-iter.

#define BATCH 2048
#define NDIM  4096
#define INDIM 512
#define BM 128
#define BN 128
#define BK 32

typedef _Float16 f16x8 __attribute__((ext_vector_type(8)));
typedef _Float16 f16x4 __attribute__((ext_vector_type(4)));
typedef float    f32x4 __attribute__((ext_vector_type(4)));

__device__ __forceinline__ void async16(const void* gsrc, void* ldst) {
  const __attribute__((address_space(1))) unsigned int* g =
      (const __attribute__((address_space(1))) unsigned int*)gsrc;
  __attribute__((address_space(3))) unsigned int* l =
      (__attribute__((address_space(3))) unsigned int*)ldst;
  __builtin_amdgcn_global_load_lds(g, l, 16, 0, 0);
}

// ---------------- prep: split+pad x into S_hi/S_lo (row-major) ----------------
__global__ void prep_x(const float* __restrict__ x,
                       _Float16* __restrict__ Sh, _Float16* __restrict__ Sl) {
  size_t i = (size_t)blockIdx.x * 256 + threadIdx.x;  // over BATCH*NDIM
  int b = (int)(i >> 12);
  int n = (int)(i & (NDIM - 1));
  float v = (n < INDIM) ? x[(size_t)b * INDIM + n] : 0.0f;
  _Float16 h = (_Float16)v;
  Sh[i] = h;
  Sl[i] = (_Float16)(v - (float)h);
}

// ---------------- prep: W -> 256*W^T hi/lo in frag-native swizzled layout ----
// Bswz element index = ((kc*256 + jg)*64 + lane)*8 + e
//   where value = W'[k][n], k = kc*32 + (lane>>4)*8 + e, n = jg*16 + (lane&15)
__global__ void prep_w(const float* __restrict__ W,
                       _Float16* __restrict__ Bh, _Float16* __restrict__ Bl) {
  __shared__ float tile[32][33];
  int k0 = blockIdx.y * 32, n0 = blockIdx.x * 32;
  int tx = threadIdx.x & 31, ty = threadIdx.x >> 5;  // 32 x 8
  for (int r = 0; r < 4; r++)
    tile[ty + r * 8][tx] = W[(size_t)(k0 + ty + r * 8) * NDIM + n0 + tx];
  __syncthreads();
  int tid = threadIdx.x;
  int jl = tid >> 7;             // 0..1 : which 16-col frag
  int lane = (tid >> 1) & 63;    // frag lane
  int hs = tid & 1;              // which 4-element half of the 8
  int fm = lane & 15, fq = lane >> 4;
  f16x4 vh, vl;
#pragma unroll
  for (int ee = 0; ee < 4; ee++) {
    float v = tile[fq * 8 + hs * 4 + ee][jl * 16 + fm] * 256.0f;
    _Float16 h = (_Float16)v;
    vh[ee] = h;
    vl[ee] = (_Float16)(v - (float)h);
  }
  size_t o = ((size_t)((k0 >> 5) * 256 + (n0 >> 4) + jl)) * 512 + lane * 8 + hs * 4;
  *(f16x4*)(Bh + o) = vh;
  *(f16x4*)(Bl + o) = vl;
}

// ---------------- one recurrence step ----------------
// MODE 0: write split fp16 next-state; MODE 1: write fp32 to d_out
template <int MODE>
__global__ __launch_bounds__(256, 2) void step_kernel(
    const _Float16* __restrict__ Ah, const _Float16* __restrict__ Al,
    const _Float16* __restrict__ Bh, const _Float16* __restrict__ Bl,  // swizzled
    _Float16* __restrict__ Dh, _Float16* __restrict__ Dl,
    float* __restrict__ Dout, int k_len) {
  // [buf][wave][hi/lo][32 rows x 32 k] — each wave's slice is private to it.
  __shared__ _Float16 sA[2][4][2][1024];

  const int tid = threadIdx.x;
  const int lane = tid & 63;
  const int w = tid >> 6;  // wave 0..3, owns rows [w*32, w*32+32)

  // XCD-aware swizzle: 8x8 block region per XCD (round-robin dispatch, id&7)
  int id = blockIdx.x;
  int xcd = id & 7, local = id >> 3;
  int lr = local & 7, lc = local >> 3;
  const int bm = ((xcd & 1) * 8 + lr) * BM;
  const int bn = ((xcd >> 1) * 8 + lc) * BN;

  const int fm = lane & 15, fq = lane >> 4;

  // ---- A staging addresses (wave-private rows, DMA, XOR k-chunk swizzle) ----
  // DMA lane -> (row = lane>>2, slot = lane&3); fetches global chunk slot^(row&3)
  const int arow = lane >> 2, aslot = lane & 3;
  const int achunk = aslot ^ (arow & 3);
  const size_t gA0 = (size_t)(bm + w * 32 + arow) * NDIM + achunk * 8;
  const size_t gA1 = (size_t)(bm + w * 32 + 16 + arow) * NDIM + achunk * 8;

  // ---- A fragment LDS element-offsets (i in {0,1}) ----
  int oA[2];
#pragma unroll
  for (int i = 0; i < 2; i++)
    oA[i] = (i * 16 + fm) * 32 + ((fq ^ (fm & 3)) * 8);

  // ---- B global frag base (swizzled layout): + kc*131072 + j*512 per use ----
  const size_t oB = (size_t)(bn >> 4) * 512 + (size_t)lane * 8;

  auto stage = [&](int kt, int b) {
    _Float16* dh = &sA[b][w][0][0];
    _Float16* dl = &sA[b][w][1][0];
    async16(Ah + gA0 + kt, dh + lane * 8);
    async16(Ah + gA1 + kt, dh + 512 + lane * 8);
    async16(Al + gA0 + kt, dl + lane * 8);
    async16(Al + gA1 + kt, dl + 512 + lane * 8);
  };

  f32x4 acc[2][8];
#pragma unroll
  for (int i = 0; i < 2; i++)
#pragma unroll
    for (int j = 0; j < 8; j++) acc[i][j] = (f32x4){0.f, 0.f, 0.f, 0.f};

  f16x8 ah[2], alo[2], bhf[8], blf[8];

#define WAITV asm volatile("s_waitcnt vmcnt(0)" ::: "memory")

#define READA(b)                                   \
  do {                                             \
    _Pragma("unroll") for (int i = 0; i < 2; i++) {\
      ah[i]  = *(const f16x8*)&sA[b][w][0][oA[i]]; \
      alo[i] = *(const f16x8*)&sA[b][w][1][oA[i]]; \
    }                                              \
  } while (0)

#define LOADB(kc)                                                   \
  do {                                                              \
    size_t kof = oB + (size_t)(kc) * 131072;                        \
    _Pragma("unroll") for (int j = 0; j < 8; j++) {                 \
      bhf[j] = *(const f16x8*)(Bh + kof + (size_t)j * 512);         \
      blf[j] = *(const f16x8*)(Bl + kof + (size_t)j * 512);         \
    }                                                               \
  } while (0)

#define MFMAS                                                                               \
  do {                                                                                      \
    _Pragma("unroll") for (int j = 0; j < 8; j++)                                           \
    _Pragma("unroll") for (int i = 0; i < 2; i++) {                                         \
      acc[i][j] = __builtin_amdgcn_mfma_f32_16x16x32_f16(ah[i],  bhf[j], acc[i][j], 0, 0, 0); \
      acc[i][j] = __builtin_amdgcn_mfma_f32_16x16x32_f16(alo[i], bhf[j], acc[i][j], 0, 0, 0); \
      acc[i][j] = __builtin_amdgcn_mfma_f32_16x16x32_f16(ah[i],  blf[j], acc[i][j], 0, 0, 0); \
    }                                                                                       \
  } while (0)

  const int nk = k_len / BK;  // 16 or 128 (even)

  stage(0, 0);
  for (int it = 0; it < nk; it += 2) {
    // ---- iter it (buf 0)
    WAITV;                     // drains stage(it) — issued one full iter ago
    READA(0);
    stage((it + 1) * BK, 1);
    LOADB(it);
    MFMAS;
    // ---- iter it+1 (buf 1)
    WAITV;                     // drains stage(it+1)
    READA(1);
    if (it + 2 < nk) stage((it + 2) * BK, 0);
    LOADB(it + 1);
    MFMAS;
  }

  // ---- epilogue: undo 256x W-scale, leaky relu, write next state / output
  // C/D 16x16 (verified): col = lane&15, row = (lane>>4)*4 + e
  const float inv = 1.0f / 256.0f;
#pragma unroll
  for (int i = 0; i < 2; i++) {
#pragma unroll
    for (int j = 0; j < 8; j++) {
#pragma unroll
      for (int e = 0; e < 4; e++) {
        int r = bm + w * 32 + i * 16 + fq * 4 + e;
        int c = bn + j * 16 + fm;
        float g = acc[i][j][e] * inv;
        float s = (g > 0.0f) ? g : 0.1f * g;
        if (MODE == 0) {
          _Float16 h = (_Float16)s;
          Dh[(size_t)r * NDIM + c] = h;
          Dl[(size_t)r * NDIM + c] = (_Float16)(s - (float)h);
        } else {
          Dout[(size_t)r * NDIM + c] = s;
        }
      }
    }
  }
#undef WAITV
#undef READA
#undef LOADB
#undef MFMAS
}

extern "C" void kernel_launch(void* const* d_in, const int* in_sizes, int n_in,
                              void* d_out, int out_size, void* d_ws, size_t ws_size,
                              hipStream_t stream) {
  const float* x = (const float*)d_in[0];  // [2048, 512]
  const float* W = (const float*)d_in[1];  // [4096, 4096]
  float* out = (float*)d_out;              // [2048, 4096]
  char* ws = (char*)d_ws;

  const size_t WT_BYTES = (size_t)NDIM * NDIM * 2;  // 32 MB each
  const size_t S_BYTES = (size_t)BATCH * NDIM * 2;  // 16 MB each
  _Float16* Wth = (_Float16*)ws;                    // B hi, swizzled
  _Float16* Wtl = (_Float16*)(ws + WT_BYTES);       // B lo, swizzled
  _Float16* SAh = (_Float16*)(ws + 2 * WT_BYTES);
  _Float16* SAl = (_Float16*)(ws + 2 * WT_BYTES + S_BYTES);
  _Float16* SBh = (_Float16*)(ws + 2 * WT_BYTES + 2 * S_BYTES);
  _Float16* SBl = (_Float16*)(ws + 2 * WT_BYTES + 3 * S_BYTES);

  prep_x<<<(BATCH * NDIM) / 256, 256, 0, stream>>>(x, SAh, SAl);
  prep_w<<<dim3(NDIM / 32, NDIM / 32), 256, 0, stream>>>(W, Wth, Wtl);

  dim3 grid((NDIM / BN) * (BATCH / BM));  // 512 linear, swizzled in-kernel
  for (int t = 1; t <= 16; t++) {
    const _Float16* ah = (t & 1) ? SAh : SBh;
    const _Float16* al = (t & 1) ? SAl : SBl;
    _Float16* dh = (t & 1) ? SBh : SAh;
    _Float16* dl = (t & 1) ? SBl : SAl;
    int klen = (t == 1) ? INDIM : NDIM;
    if (t < 16)
      step_kernel<0><<<grid, 256, 0, stream>>>(ah, al, Wth, Wtl, dh, dl, nullptr, klen);
    else
      step_kernel<1><<<grid, 256, 0, stream>>>(ah, al, Wth, Wtl, nullptr, nullptr, out, klen);
  }
}